// Round 11
// baseline (201.105 us; speedup 1.0000x reference)
//
#include <hip/hip_runtime.h>
#include <hip/hip_bf16.h>
#include <cstdint>
#include <cstddef>

#define NATOMS 8192
#define DIM 32
#define NSEQ 4096
#define KSPLIT 16
#define BM 256
#define BK 32
#define KPB (NATOMS / KSPLIT)   // 512 k per block
#define NT (KPB / BK)           // 16 tiles
#define FRONT_NB (NATOMS / 8 + NSEQ * DIM / 256)  // 1536

typedef __attribute__((address_space(1))) const void GV;
typedef __attribute__((address_space(3))) void LV;
using bf16x8 = __attribute__((ext_vector_type(8))) short;
using f32x4  = __attribute__((ext_vector_type(4))) float;
using u32x2  = __attribute__((ext_vector_type(2))) unsigned int;

__device__ __forceinline__ void async16(void* lds, const void* g) {
  __builtin_amdgcn_global_load_lds((GV*)g, (LV*)lds, 16, 0, 0);
}
// aux=2 -> NT: streaming, minimize cache retention (dead-after-read data).
__device__ __forceinline__ void async16nt(void* lds, const void* g) {
  __builtin_amdgcn_global_load_lds((GV*)g, (LV*)lds, 16, 0, 2);
}
__device__ __forceinline__ uint32_t pkbf(float lo, float hi) {
  union { __hip_bfloat16 b[2]; uint32_t u; } v;
  v.b[0] = __float2bfloat16(lo);
  v.b[1] = __float2bfloat16(hi);
  return v.u;
}
__device__ __forceinline__ float ubf(ushort u) {
  union { ushort u; __hip_bfloat16 b; } v;
  v.u = u;
  return __bfloat162float(v.b);
}
__device__ __forceinline__ ushort bfr(float a) {
  union { __hip_bfloat16 b; ushort u; } v;
  v.b = __float2bfloat16(a);
  return v.u;
}
union U8 { uint32_t u[4]; bf16x8 v; };

// bf16 tile image: per (ks,rb,t) tile of 256 rows x 32 k: row r = 64B = 4
// 16B slots; slot s holds k-chunk s ^ ((r>>1)&3).
__device__ __forceinline__ int aslot(int r, int g) { return g ^ ((r >> 1) & 3); }
__device__ __forceinline__ int hslot(int n, int g) { return g ^ ((n >> 1) & 3); }

// ---------------------------------------------------------------------------
// Shared tail: h-compute part. xsl[256][32] in LDS holds the reduced rows.
// Each thread: preload W column (32 VGPR), then 32 rows x 8 ds_read_b128.
// ---------------------------------------------------------------------------
__device__ __forceinline__ void h_tail(const float* xsl, const float* Wl,
                                       const float* bn, ushort* hTout,
                                       int row0, int tid) {
  float wcol[DIM];
  const int c = tid & 31;
#pragma unroll
  for (int d = 0; d < DIM; ++d) wcol[d] = Wl[d * DIM + c];
  const float bb = bn[c];
#pragma unroll 1
  for (int it = 0; it < 32; ++it) {
    const int r = it * 8 + (tid >> 5);
    float a = bb;
    const f32x4* xr = (const f32x4*)(xsl + r * DIM);
#pragma unroll
    for (int q = 0; q < 8; ++q) {
      f32x4 x4 = xr[q];
      a += x4.x * wcol[q * 4] + x4.y * wcol[q * 4 + 1] +
           x4.z * wcol[q * 4 + 2] + x4.w * wcol[q * 4 + 3];
    }
    hTout[(size_t)c * NATOMS + row0 + r] = bfr(fmaxf(a, 0.f));
  }
}

// ---------------------------------------------------------------------------
// Layer-0 GEMM + fused split-K reduce: P0(fp32) = A(fp32->bf16) @ hTa;
// writes Abf tile image; last block per rb reduces -> xs, hTb.
// ---------------------------------------------------------------------------
__global__ __launch_bounds__(256, 2)
void cpi_gemm1(const float* __restrict__ A, const ushort* __restrict__ hTin,
               float* __restrict__ P, ushort* __restrict__ Abf,
               int* __restrict__ cnt, const float* __restrict__ Wn,
               const float* __restrict__ bn, float* __restrict__ xs,
               ushort* __restrict__ hTout) {
  __shared__ float  Ab[2][BM * BK];   // 64 KiB (tail aliases 36 KB of this)
  __shared__ ushort Hb[2][DIM * BK];  // 4 KiB
  __shared__ int lastFlag;

  const int tid  = threadIdx.x;
  const int wave = tid >> 6;
  const int lane = tid & 63;
  const int l15  = lane & 15;
  const int l4   = lane >> 4;
  const int rb   = blockIdx.x & 31;
  const int ks   = blockIdx.x >> 5;
  const int row0 = rb * BM;
  const int k0   = ks * KPB;

  f32x4 acc[4][2];
#pragma unroll
  for (int rt = 0; rt < 4; ++rt)
#pragma unroll
    for (int ct = 0; ct < 2; ++ct) acc[rt][ct] = {0.f, 0.f, 0.f, 0.f};

  auto stage = [&](int buf, int t) {
    const int kb = k0 + t * BK;
#pragma unroll
    for (int i = 0; i < 8; ++i) {
      const int D = (wave * 8 + i) * 64 + lane;  // fp32 16B chunk 0..2047
      const int r = D >> 3;
      const int c = D & 7;
      const float* src =
          A + (size_t)(row0 + r) * NATOMS + kb + ((c ^ (r & 7)) << 2);
      async16nt(&Ab[buf][(wave * 8 + i) * 256], src);  // NT: dead after read
    }
    if (wave < 2) {  // h tile: 2KB = 128 chunks
      const int E = wave * 64 + lane;
      const int n = E >> 2;
      const int s = E & 3;
      const ushort* src = hTin + (size_t)n * NATOMS + kb + (hslot(n, s) << 3);
      async16(&Hb[buf][wave * 512], src);
    }
  };

  stage(0, 0);
  asm volatile("s_waitcnt vmcnt(0)" ::: "memory");
  __syncthreads();

  int cur = 0;
#pragma unroll 1
  for (int t = 0; t < NT; ++t) {
    if (t + 1 < NT) stage(cur ^ 1, t + 1);

    const float*  Ac = &Ab[cur][0];
    const ushort* Hc = &Hb[cur][0];

    bf16x8 av[4];
#pragma unroll
    for (int rt = 0; rt < 4; ++rt) {
      const int r = wave * 64 + rt * 16 + l15;
      const float4 f0 =
          *(const float4*)(Ac + r * 32 + (((2 * l4) ^ (r & 7)) << 2));
      const float4 f1 =
          *(const float4*)(Ac + r * 32 + (((2 * l4 + 1) ^ (r & 7)) << 2));
      U8 u;
      u.u[0] = pkbf(f0.x, f0.y);
      u.u[1] = pkbf(f0.z, f0.w);
      u.u[2] = pkbf(f1.x, f1.y);
      u.u[3] = pkbf(f1.z, f1.w);
      av[rt] = u.v;
    }
    bf16x8 bv[2];
#pragma unroll
    for (int ct = 0; ct < 2; ++ct) {
      const int n = ct * 16 + l15;
      bv[ct] = *(const bf16x8*)(Hc + n * 32 + (hslot(n, l4) << 3));
    }

    ushort* Tb = Abf + (((size_t)ks * 32 + rb) * 16 + t) * (BM * BK);
#pragma unroll
    for (int rt = 0; rt < 4; ++rt) {
      const int r = wave * 64 + rt * 16 + l15;
      *(bf16x8*)(Tb + r * 32 + (aslot(r, l4) << 3)) = av[rt];
    }

#pragma unroll
    for (int rt = 0; rt < 4; ++rt)
#pragma unroll
      for (int ct = 0; ct < 2; ++ct)
        acc[rt][ct] = __builtin_amdgcn_mfma_f32_16x16x32_bf16(
            av[rt], bv[ct], acc[rt][ct], 0, 0, 0);

    asm volatile("s_waitcnt vmcnt(4)" ::: "memory");
    __syncthreads();
    cur ^= 1;
  }

  float* Pp = P + ((((size_t)ks * 32 + rb) * 4 + wave) * 8) * 256;
#pragma unroll
  for (int rt = 0; rt < 4; ++rt)
#pragma unroll
    for (int ct = 0; ct < 2; ++ct)
      *(f32x4*)(Pp + (rt * 2 + ct) * 256 + lane * 4) = acc[rt][ct];

  // ---- fused split-K reduce: last block per rb ----
  asm volatile("s_waitcnt vmcnt(0)" ::: "memory");
  __syncthreads();
  if (tid == 0) {
    int c = __hip_atomic_fetch_add(&cnt[rb], 1, __ATOMIC_ACQ_REL,
                                   __HIP_MEMORY_SCOPE_AGENT);
    lastFlag = (c == KSPLIT - 1);
  }
  __syncthreads();
  if (!lastFlag) return;

  float* xsl = (float*)&Ab[0][0];     // 32 KB
  float* Wl  = xsl + 256 * DIM;       // +4 KB
  for (int i = tid; i < DIM * DIM; i += 256) Wl[i] = Wn[i];

  const int colq = lane & 15, rq = lane >> 4;
#pragma unroll
  for (int f = 0; f < 8; ++f) {
    const size_t base = ((size_t)(rb * 4 + wave) * 8 + f) * 256 + lane * 4;
    const int rt = f >> 1, ct = f & 1;
    f32x4 a4;
#pragma unroll
    for (int i = 0; i < 4; ++i) {
      const int row = wave * 64 + rt * 16 + rq * 4 + i;
      a4[i] = xs[(size_t)(row0 + row) * DIM + ct * 16 + colq];
    }
#pragma unroll
    for (int k = 0; k < KSPLIT; ++k) {
      f32x4 v = __builtin_nontemporal_load(
          (const f32x4*)(P + (size_t)k * (NATOMS * DIM) + base));
      a4.x += v.x; a4.y += v.y; a4.z += v.z; a4.w += v.w;
    }
#pragma unroll
    for (int i = 0; i < 4; ++i) {
      const int row = wave * 64 + rt * 16 + rq * 4 + i;
      const int col = ct * 16 + colq;
      xs[(size_t)(row0 + row) * DIM + col] = a4[i];
      xsl[row * DIM + col] = a4[i];
    }
  }
  __syncthreads();
  h_tail(xsl, Wl, bn, hTout, row0, tid);
}

// ---------------------------------------------------------------------------
// Layers 1/2 GEMM + fused reduce: Pb(bf16) = Abf @ hTin, MFMA, 3-deep
// counted pipeline; last block per rb reduces -> xs (+ hTout if doH).
// ---------------------------------------------------------------------------
__global__ __launch_bounds__(256, 2)
void cpi_gemm2(const ushort* __restrict__ Abf, const ushort* __restrict__ hTin,
               ushort* __restrict__ Pb, const int ntA, int* __restrict__ cnt,
               const float* __restrict__ Wn, const float* __restrict__ bn,
               float* __restrict__ xs, ushort* __restrict__ hTout,
               const int doH) {
  __shared__ ushort Ab[3][BM * BK];   // 48 KiB (tail aliases 36 KB)
  __shared__ ushort Hb[3][DIM * BK];  // 6 KiB
  __shared__ int lastFlag;

  const int tid  = threadIdx.x;
  const int wave = tid >> 6;
  const int lane = tid & 63;
  const int l15  = lane & 15;
  const int l4   = lane >> 4;
  const int rb   = blockIdx.x & 31;
  const int ks   = blockIdx.x >> 5;
  const int row0 = rb * BM;
  const int k0   = ks * KPB;

  f32x4 acc[4][2];
#pragma unroll
  for (int rt = 0; rt < 4; ++rt)
#pragma unroll
    for (int ct = 0; ct < 2; ++ct) acc[rt][ct] = {0.f, 0.f, 0.f, 0.f};

  auto stage = [&](int buf, int t) {
    const ushort* Tb = Abf + (((size_t)ks * 32 + rb) * 16 + t) * (BM * BK);
#pragma unroll
    for (int i = 0; i < 4; ++i) {  // 16KB linear copy
      const ushort* src = Tb + ((wave * 4 + i) * 64 + lane) * 8;
      void* dst = &Ab[buf][(wave * 4 + i) * 512];
      if (ntA)
        async16nt(dst, src);  // layer 2: Abf dead after this read
      else
        async16(dst, src);
    }
    if (wave < 2) {
      const int kb = k0 + t * BK;
      const int E = wave * 64 + lane;
      const int n = E >> 2;
      const int s = E & 3;
      const ushort* src = hTin + (size_t)n * NATOMS + kb + (hslot(n, s) << 3);
      async16(&Hb[buf][wave * 512], src);
    }
  };

  stage(0, 0);
  stage(1, 1);

#pragma unroll 1
  for (int t = 0; t < NT; ++t) {
    if (t + 1 < NT) {
      if (wave < 2)
        asm volatile("s_waitcnt vmcnt(5)" ::: "memory");
      else
        asm volatile("s_waitcnt vmcnt(4)" ::: "memory");
    } else {
      asm volatile("s_waitcnt vmcnt(0)" ::: "memory");
    }
    __syncthreads();
    if (t + 2 < NT) stage((t + 2) % 3, t + 2);

    const ushort* Ac = &Ab[t % 3][0];
    const ushort* Hc = &Hb[t % 3][0];

    bf16x8 av[4], bv[2];
#pragma unroll
    for (int rt = 0; rt < 4; ++rt) {
      const int r = wave * 64 + rt * 16 + l15;
      av[rt] = *(const bf16x8*)(Ac + r * 32 + (aslot(r, l4) << 3));
    }
#pragma unroll
    for (int ct = 0; ct < 2; ++ct) {
      const int n = ct * 16 + l15;
      bv[ct] = *(const bf16x8*)(Hc + n * 32 + (hslot(n, l4) << 3));
    }

#pragma unroll
    for (int rt = 0; rt < 4; ++rt)
#pragma unroll
      for (int ct = 0; ct < 2; ++ct)
        acc[rt][ct] = __builtin_amdgcn_mfma_f32_16x16x32_bf16(
            av[rt], bv[ct], acc[rt][ct], 0, 0, 0);
  }

  ushort* Pp = Pb + ((((size_t)ks * 32 + rb) * 4 + wave) * 8) * 256;
#pragma unroll
  for (int rt = 0; rt < 4; ++rt)
#pragma unroll
    for (int ct = 0; ct < 2; ++ct) {
      u32x2 u;
      u.x = pkbf(acc[rt][ct].x, acc[rt][ct].y);
      u.y = pkbf(acc[rt][ct].z, acc[rt][ct].w);
      *(u32x2*)(Pp + (rt * 2 + ct) * 256 + lane * 4) = u;
    }

  // ---- fused split-K reduce: last block per rb ----
  asm volatile("s_waitcnt vmcnt(0)" ::: "memory");
  __syncthreads();
  if (tid == 0) {
    int c = __hip_atomic_fetch_add(&cnt[rb], 1, __ATOMIC_ACQ_REL,
                                   __HIP_MEMORY_SCOPE_AGENT);
    lastFlag = (c == KSPLIT - 1);
  }
  __syncthreads();
  if (!lastFlag) return;

  float* xsl = (float*)&Ab[0][0];     // 32 KB
  float* Wl  = xsl + 256 * DIM;       // +4 KB
  if (doH)
    for (int i = tid; i < DIM * DIM; i += 256) Wl[i] = Wn[i];

  const int colq = lane & 15, rq = lane >> 4;
#pragma unroll
  for (int f = 0; f < 8; ++f) {
    const size_t base = ((size_t)(rb * 4 + wave) * 8 + f) * 256 + lane * 4;
    const int rt = f >> 1, ct = f & 1;
    f32x4 a4;
#pragma unroll
    for (int i = 0; i < 4; ++i) {
      const int row = wave * 64 + rt * 16 + rq * 4 + i;
      a4[i] = xs[(size_t)(row0 + row) * DIM + ct * 16 + colq];
    }
#pragma unroll
    for (int k = 0; k < KSPLIT; ++k) {
      u32x2 v = __builtin_nontemporal_load(
          (const u32x2*)(Pb + (size_t)k * (NATOMS * DIM) + base));
      a4.x += ubf((ushort)(v.x & 0xffff));
      a4.y += ubf((ushort)(v.x >> 16));
      a4.z += ubf((ushort)(v.y & 0xffff));
      a4.w += ubf((ushort)(v.y >> 16));
    }
#pragma unroll
    for (int i = 0; i < 4; ++i) {
      const int row = wave * 64 + rt * 16 + rq * 4 + i;
      const int col = ct * 16 + colq;
      xs[(size_t)(row0 + row) * DIM + col] = a4[i];
      if (doH) xsl[row * DIM + col] = a4[i];
    }
  }
  if (doH) {
    __syncthreads();
    h_tail(xsl, Wl, bn, hTout, row0, tid);
  }
}

// ---------------------------------------------------------------------------
// Front kernel: [0,1024): xs gather + hTa = bf16(relu(xs@W0+b0));
// [1024,1536): word vectors; block 1536: zero split-K counters.
// ---------------------------------------------------------------------------
__global__ __launch_bounds__(256)
void cpi_front(const int* __restrict__ fp, const float* __restrict__ embfp,
               const float* __restrict__ W, const float* __restrict__ b,
               float* __restrict__ xs, ushort* __restrict__ hT,
               const int* __restrict__ words, const float* __restrict__ embw,
               float* __restrict__ wout, int* __restrict__ cnt) {
  if (blockIdx.x == FRONT_NB) {  // counter-zero block (re-armed every call)
    if (threadIdx.x < 96) cnt[threadIdx.x] = 0;
    return;
  }
  if (blockIdx.x >= NATOMS / 8) {  // words part (block-uniform branch)
    const int i = (blockIdx.x - NATOMS / 8) * 256 + threadIdx.x;
    wout[i] = embw[(size_t)words[i >> 5] * DIM + (i & 31)];
    return;
  }
  __shared__ float xsl[8][DIM];
  __shared__ float Wl[DIM][DIM];
  const int tid = threadIdx.x;
  const int col = tid & 31;
  const int r8  = tid >> 5;
  const int row = blockIdx.x * 8 + r8;
  const int f   = fp[row];
  const float v = embfp[(size_t)f * DIM + col];
  xs[(size_t)row * DIM + col] = v;
  xsl[r8][col] = v;
#pragma unroll
  for (int i = 0; i < 4; ++i) {
    const int idx = tid + i * 256;
    ((float*)Wl)[idx] = W[idx];
  }
  __syncthreads();
  float a = b[col];
#pragma unroll
  for (int d = 0; d < DIM; ++d) a += xsl[r8][d] * Wl[d][col];
  hT[(size_t)col * NATOMS + row] = bfr(fmaxf(a, 0.f));
}

extern "C" void kernel_launch(void* const* d_in, const int* in_sizes, int n_in,
                              void* d_out, int out_size, void* d_ws, size_t ws_size,
                              hipStream_t stream) {
  const int*   fp    = (const int*)d_in[0];
  const float* adj   = (const float*)d_in[1];
  const int*   words = (const int*)d_in[2];
  const float* embfp = (const float*)d_in[3];
  const float* embw  = (const float*)d_in[4];
  const float* Wg    = (const float*)d_in[5];
  const float* bg    = (const float*)d_in[6];

  float* out = (float*)d_out;
  float* xs  = out;                 // [8192*32] final compound_vector
  float* wv  = out + NATOMS * DIM;  // [4096*32] word vectors

  float*  P   = (float*)d_ws;                               // 16 MB fp32 P0
  ushort* Pb  = (ushort*)P;                                 // 8 MB bf16 P1/P2
  ushort* Abf = (ushort*)(P + (size_t)KSPLIT * NATOMS * DIM);  // 128 MB bf16 A
  ushort* hTa = Abf + (size_t)NATOMS * NATOMS;              // 512 KB bf16 h^T
  ushort* hTb = hTa + (size_t)DIM * NATOMS;                 // 512 KB bf16 h^T
  int*    cnt = (int*)(hTb + (size_t)DIM * NATOMS);         // 96 counters

  // front: gather + h0 -> hTa, words, zero counters
  cpi_front<<<dim3(FRONT_NB + 1), dim3(256), 0, stream>>>(
      fp, embfp, Wg, bg, xs, hTa, words, embw, wv, cnt);

  // layer 0: fp32 A (NT) -> MFMA + Abf image; fused reduce -> xs, hTb
  cpi_gemm1<<<dim3(512), dim3(256), 0, stream>>>(
      adj, hTa, P, Abf, cnt, Wg + DIM * DIM, bg + DIM, xs, hTb);

  // layer 1: Abf @ hTb; fused reduce -> xs, hTa
  cpi_gemm2<<<dim3(512), dim3(256), 0, stream>>>(
      Abf, hTb, Pb, 0, cnt + 32, Wg + 2 * DIM * DIM, bg + 2 * DIM, xs, hTa, 1);

  // layer 2: Abf (NT) @ hTa; fused reduce -> xs only
  cpi_gemm2<<<dim3(512), dim3(256), 0, stream>>>(
      Abf, hTa, Pb, 1, cnt + 64, Wg, bg, xs, hTb, 0);
}